// Round 11
// baseline (156.154 us; speedup 1.0000x reference)
//
#include <hip/hip_runtime.h>
#include <stdint.h>

#define S_LEN 2048
#define D_MODEL 1024
#define NH 16
#define DKV 64

typedef unsigned short u16;
typedef __bf16 bf16x8 __attribute__((ext_vector_type(8)));
typedef float f32x4 __attribute__((ext_vector_type(4)));

__device__ __forceinline__ u16 f2bf(float f) {
  union { float f; uint32_t u; } v; v.f = f;
  uint32_t r = v.u + 0x7FFFu + ((v.u >> 16) & 1u);
  return (u16)(r >> 16);
}
// pack two positive floats to bf16x2 (cheap round; softmax-normalized later)
// NOTE round-3/4 post-mortem: hand-asm v_cvt_pk/v_exp here caused a deterministic
// trans-hazard corruption (compiler can't insert wait-states inside opaque asm).
// Use compiler-known ops only.
__device__ __forceinline__ uint32_t pkbf(float lo, float hi) {
  union { float f; uint32_t u; } a, b; a.f = lo; b.f = hi;
  return ((b.u + 0x8000u) & 0xFFFF0000u) | ((a.u + 0x8000u) >> 16);
}
// async global->LDS 16B: lds dest is WAVE-UNIFORM base; HW adds lane*16
__device__ __forceinline__ void gl16(const u16* g, u16* l) {
  __builtin_amdgcn_global_load_lds(
      (const __attribute__((address_space(1))) unsigned int*)g,
      (__attribute__((address_space(3))) unsigned int*)l, 16, 0, 0);
}

// ---------- fused preprocessing: conv QKV + transpose Wq/Wk/Wv + transpose Wo ----------
// 1D grid: [0,6144) conv, [6144,9216) qkvw transpose, [9216,10240) Wo transpose
__global__ __launch_bounds__(256) void prep_k(
    const float* __restrict__ Q, const float* __restrict__ K,
    const float* __restrict__ V, const float* __restrict__ Wq,
    const float* __restrict__ Wk, const float* __restrict__ Wv,
    const float* __restrict__ Wo, u16* __restrict__ QKVb,
    u16* __restrict__ Wqt, u16* __restrict__ Wkt, u16* __restrict__ Wvt,
    u16* __restrict__ Wot) {
  __shared__ float tile[32][33];
  const int idx = blockIdx.x;
  if (idx < 6144) {
    const int z = idx >> 11, blk = idx & 2047;
    const float* src = (z == 0) ? Q : (z == 1) ? K : V;
    u16* dst = QKVb + (size_t)z * S_LEN * D_MODEL;
    size_t i = ((size_t)blk * 256 + threadIdx.x) * 4;
    const float4 v = *(const float4*)(src + i);
    union { u16 h[4]; uint2 u2; } o;
    o.h[0] = f2bf(v.x); o.h[1] = f2bf(v.y); o.h[2] = f2bf(v.z); o.h[3] = f2bf(v.w);
    *(uint2*)(dst + i) = o.u2;
    return;
  }
  const float* ip; u16* op; int R, C, r0, c0;
  if (idx < 9216) {
    int t = idx - 6144;
    int which = t >> 10, head = (t & 1023) >> 6, tl = t & 63;
    ip = ((which == 0) ? Wq : (which == 1) ? Wk : Wv) + (size_t)head * D_MODEL * DKV;
    op = ((which == 0) ? Wqt : (which == 1) ? Wkt : Wvt) + (size_t)head * D_MODEL * DKV;
    R = D_MODEL; C = DKV; c0 = (tl & 1) * 32; r0 = (tl >> 1) * 32;
  } else {
    int t = idx - 9216;
    ip = Wo; op = Wot; R = D_MODEL; C = D_MODEL;
    c0 = (t & 31) * 32; r0 = (t >> 5) * 32;
  }
  int tr = threadIdx.x >> 5, tc = threadIdx.x & 31;
#pragma unroll
  for (int i = 0; i < 4; i++)
    tile[tr + i * 8][tc] = ip[(size_t)(r0 + tr + i * 8) * C + c0 + tc];
  __syncthreads();
#pragma unroll
  for (int i = 0; i < 4; i++) {
    int c = tr + i * 8;
    op[(size_t)(c0 + c) * R + r0 + tc] = f2bf(tile[tc][c]);
  }
}

// ---------- projection GEMM: 128x64 tile, BK=64, 3-buf 2-deep counted-vmcnt ----------
// Grid 768 = 3 blocks/CU exactly. XCD-swizzled: l = (bid%8)*96 + bid/8.
__global__ __launch_bounds__(256, 2) void proj_gemm_k(
    const u16* __restrict__ qkvb, const u16* __restrict__ Wqt,
    const u16* __restrict__ Wkt, const u16* __restrict__ Wvt,
    const float* __restrict__ bq, const float* __restrict__ bk,
    const float* __restrict__ bv,
    u16* __restrict__ qb, u16* __restrict__ kb, u16* __restrict__ vT) {
  const int bid = blockIdx.x;
  const int l = (bid & 7) * 96 + (bid >> 3);   // bijective: 768 = 8*96
  const int z = l >> 8, rem = l & 255;
  const int m0 = (rem >> 4) * 128, n0 = (rem & 15) * 64;
  const u16* A = qkvb + (size_t)z * S_LEN * D_MODEL;
  const u16* Bt = (z == 0) ? Wqt : (z == 1) ? Wkt : Wvt;
  const float* bias = (z == 0) ? bq : (z == 1) ? bk : bv;
  const float scale = (z == 0) ? 0.18033688f : 1.0f;  // (1/8)*log2(e) folded into q

  // u16: A x3 bufs @0 (16KB each), B x3 bufs @24576 (8KB each) -> 72KB, 2 blocks/CU
  __shared__ __align__(16) u16 smem[36864];
  const int tid = threadIdx.x;
  const int w = tid >> 6, lane = tid & 63, quad = lane >> 4, l15 = lane & 15;
  const int wm = (w >> 1) * 64, wn = (w & 1) * 32;
  const int pbA = w * 256, pbB = w * 128;

  f32x4 acc[4][2] = {};

  {  // prologue: k-step 0 -> buf0, k-step 1 -> buf1 (program order = vmcnt order)
#pragma unroll
    for (int b = 0; b < 2; b++) {
      const int k0 = b * 64;
      u16* As = smem + b * 8192;
      u16* Bs = smem + 24576 + b * 4096;
#pragma unroll
      for (int e = 0; e < 4; e++) {
        int p = pbA + e * 64 + lane;
        int r = p >> 3, cg = (p & 7) ^ (r & 7);
        gl16(&A[(size_t)(m0 + r) * D_MODEL + k0 + cg * 8], As + (pbA + e * 64) * 8);
      }
#pragma unroll
      for (int e = 0; e < 2; e++) {
        int p = pbB + e * 64 + lane;
        int r = p >> 3, cg = (p & 7) ^ (r & 7);
        gl16(&Bt[(size_t)(n0 + r) * D_MODEL + k0 + cg * 8], Bs + (pbB + e * 64) * 8);
      }
    }
  }
#pragma unroll
  for (int it = 0; it < 16; it++) {
    const int rd = it % 3;  // compile-time constant after full unroll
    if (it < 15) asm volatile("s_waitcnt vmcnt(6)" ::: "memory");
    else         asm volatile("s_waitcnt vmcnt(0)" ::: "memory");
    __builtin_amdgcn_s_barrier();
    __builtin_amdgcn_sched_barrier(0);  // pin: nothing (esp. ds_read/gl16) above barrier
    if (it < 14) {
      const int wr = (rd + 2) % 3;
      const int k0 = (it + 2) * 64;
      u16* As = smem + wr * 8192;
      u16* Bs = smem + 24576 + wr * 4096;
#pragma unroll
      for (int e = 0; e < 4; e++) {
        int p = pbA + e * 64 + lane;
        int r = p >> 3, cg = (p & 7) ^ (r & 7);
        gl16(&A[(size_t)(m0 + r) * D_MODEL + k0 + cg * 8], As + (pbA + e * 64) * 8);
      }
#pragma unroll
      for (int e = 0; e < 2; e++) {
        int p = pbB + e * 64 + lane;
        int r = p >> 3, cg = (p & 7) ^ (r & 7);
        gl16(&Bt[(size_t)(n0 + r) * D_MODEL + k0 + cg * 8], Bs + (pbB + e * 64) * 8);
      }
    }
    const u16* As = smem + rd * 8192;
    const u16* Bs = smem + 24576 + rd * 4096;
#pragma unroll
    for (int kc = 0; kc < 2; kc++) {
      bf16x8 af[4], bfr[2];
      const int c = kc * 4 + quad;
#pragma unroll
      for (int t = 0; t < 4; t++) {
        int ma = wm + t * 16 + l15;
        af[t] = *(const bf16x8*)&As[(ma * 8 + (c ^ (ma & 7))) * 8];
      }
#pragma unroll
      for (int t = 0; t < 2; t++) {
        int na = wn + t * 16 + l15;
        bfr[t] = *(const bf16x8*)&Bs[(na * 8 + (c ^ (na & 7))) * 8];
      }
      __builtin_amdgcn_s_setprio(1);
#pragma unroll
      for (int tm = 0; tm < 4; tm++)
#pragma unroll
        for (int tn = 0; tn < 2; tn++)
          acc[tm][tn] = __builtin_amdgcn_mfma_f32_16x16x32_bf16(af[tm], bfr[tn], acc[tm][tn], 0, 0, 0);
      __builtin_amdgcn_s_setprio(0);
    }
  }

  if (z < 2) {
    u16* O = (z == 0) ? qb : kb;
#pragma unroll
    for (int tm = 0; tm < 4; tm++)
#pragma unroll
      for (int tn = 0; tn < 2; tn++)
#pragma unroll
        for (int r = 0; r < 4; r++) {
          int row = m0 + wm + tm * 16 + quad * 4 + r;
          int col = n0 + wn + tn * 16 + l15;
          O[(size_t)row * D_MODEL + col] = f2bf((acc[tm][tn][r] + bias[col]) * scale);
        }
  } else {
#pragma unroll
    for (int tm = 0; tm < 4; tm++)
#pragma unroll
      for (int tn = 0; tn < 2; tn++) {
        int col = n0 + wn + tn * 16 + l15;
        int row0 = m0 + wm + tm * 16 + quad * 4;
        float b = bias[col];
        union { u16 h[4]; uint2 u2; } o;
#pragma unroll
        for (int r = 0; r < 4; r++) o.h[r] = f2bf(acc[tm][tn][r] + b);
        *(uint2*)&vT[(size_t)col * S_LEN + row0] = o.u2;
      }
  }
}

// ---------- attention: 32q-per-wave REUSE + 4-buf 3-deep counted-vmcnt ----------
// (round-10 state; round-9/10 differencing puts this at ~33.6 us)
__global__ __launch_bounds__(512) void attn_k(
    const u16* __restrict__ qb, const u16* __restrict__ kb,
    const u16* __restrict__ vT, u16* __restrict__ conc) {
  const int bid = blockIdx.x;
  const int l = (bid & 7) * 32 + (bid >> 3);   // bijective: 256 = 8*32
  const int h = l >> 4, qblk = (l & 15) * 128;
  const int tid = threadIdx.x;
  const int w = tid >> 6, lane = tid & 63, quad = lane >> 4, l15 = lane & 15;
  const int half = w >> 2, qg = w & 3;
  const int q0 = qblk + qg * 32;

  // u16 layout: K[2 half][4 buf][2048] @0 (32KB), V[2][4][2048] @16384 (32KB),
  //             P[8 waves][32*56] @32768 (28KB) -> 92KB, 1 block/CU (grid=256 anyway).
  // epilogue overlays @0 as float OshF[8][2][16][68] + lshF[8][2][16] (70.7KB < 92KB)
  __shared__ __align__(16) u16 smem[47104];
  u16* Kh = smem + half * 8192;
  u16* Vh = smem + 16384 + half * 8192;
  u16* Pw = smem + 32768 + w * 1792;

  // Q B-frags for TWO 16-row groups (qi): n=q=l15, k=dk=kc*32+quad*8+j
  bf16x8 qf[2][2];
#pragma unroll
  for (int qi = 0; qi < 2; qi++)
#pragma unroll
    for (int kc = 0; kc < 2; kc++)
      qf[qi][kc] = *(const bf16x8*)&qb[(size_t)(q0 + qi * 16 + l15) * D_MODEL + h * 64 + kc * 32 + quad * 8];

  const u16* kbase = kb + (size_t)h * 64;
  const u16* vbase = vT + (size_t)(h * 64) * S_LEN;

  // per-wave staging: 4 waves per half cover the 256 16B-chunks of each K/V tile
  const int p = qg * 64 + lane;                   // 0..255
  const int kr = p >> 3, kcg = (p & 7) ^ (kr & 7);
  const int vr = p >> 2, vcg = (p & 3) ^ (vr & 3);
  const size_t kgoff = (size_t)kr * D_MODEL + kcg * 8;
  const size_t vgoff = (size_t)vr * S_LEN + vcg * 8;
  const int ldsoff = qg * 512;                    // wave-uniform dest (HW adds lane*16)

  f32x4 oacc[2][4] = {};
  float lsum0 = 0.f, lsum1 = 0.f;

  {  // prologue: stage slots 0,1,2 (program order = vmcnt order)
#pragma unroll
    for (int s = 0; s < 3; s++) {
      const int t0 = half * 1024 + s * 32;
      gl16(kbase + (size_t)t0 * D_MODEL + kgoff, Kh + s * 2048 + ldsoff);
      gl16(vbase + t0 + vgoff, Vh + s * 2048 + ldsoff);
    }
  }

#pragma unroll
  for (int it = 0; it < 32; it++) {
    const int rd = it & 3;  // compile-time constant after full unroll
    if (it < 30)       asm volatile("s_waitcnt vmcnt(4)" ::: "memory");
    else if (it == 30) asm volatile("s_waitcnt vmcnt(2)" ::: "memory");
    else               asm volatile("s_waitcnt vmcnt(0)" ::: "memory");
    __builtin_amdgcn_s_barrier();   // all waves' buf[rd] chunks visible
    __builtin_amdgcn_sched_barrier(0);  // pin: nothing (esp. ds_read/gl16) above barrier
    if (it < 29) {                  // prefetch it+3 into buf[(it+3)&3]
      const int wr = (it + 3) & 3;
      const int t0n = half * 1024 + (it + 3) * 32;
      gl16(kbase + (size_t)t0n * D_MODEL + kgoff, Kh + wr * 2048 + ldsoff);
      gl16(vbase + t0n + vgoff, Vh + wr * 2048 + ldsoff);
    }
    const u16* Kc = Kh + rd * 2048;
    const u16* Vc = Vh + rd * 2048;

    // Sᵀ = K·Qᵀ : each K frag read feeds BOTH qi groups (2x reuse)
    f32x4 sacc[2][2] = {};
    __builtin_amdgcn_s_setprio(1);
#pragma unroll
    for (int kc = 0; kc < 2; kc++)
#pragma unroll
      for (int tn = 0; tn < 2; tn++) {
        int rr = tn * 16 + l15;
        bf16x8 ka = *(const bf16x8*)&Kc[(rr * 8 + ((kc * 4 + quad) ^ (rr & 7))) * 8];
        sacc[0][tn] = __builtin_amdgcn_mfma_f32_16x16x32_bf16(ka, qf[0][kc], sacc[0][tn], 0, 0, 0);
        sacc[1][tn] = __builtin_amdgcn_mfma_f32_16x16x32_bf16(ka, qf[1][kc], sacc[1][tn], 0, 0, 0);
      }
    __builtin_amdgcn_s_setprio(0);

    // p = 2^s (log2e folded into q); lane holds Sᵀ[t=tn*16+quad*4+r][q=l15] per qi
#pragma unroll
    for (int qi = 0; qi < 2; qi++)
#pragma unroll
      for (int tn = 0; tn < 2; tn++) {
        float p0 = __builtin_amdgcn_exp2f(sacc[qi][tn][0]);
        float p1 = __builtin_amdgcn_exp2f(sacc[qi][tn][1]);
        float p2 = __builtin_amdgcn_exp2f(sacc[qi][tn][2]);
        float p3 = __builtin_amdgcn_exp2f(sacc[qi][tn][3]);
        if (qi == 0) lsum0 += (p0 + p1) + (p2 + p3);
        else         lsum1 += (p0 + p1) + (p2 + p3);
        uint2 pw2; pw2.x = pkbf(p0, p1); pw2.y = pkbf(p2, p3);
        *(uint2*)&Pw[(qi * 16 + l15) * 56 + tn * 16 + quad * 4] = pw2;
      }

    // O += P·V : each V frag read feeds BOTH qi groups (2x reuse)
    bf16x8 pa0 = *(const bf16x8*)&Pw[(l15) * 56 + quad * 8];
    bf16x8 pa1 = *(const bf16x8*)&Pw[(16 + l15) * 56 + quad * 8];
    __builtin_amdgcn_s_setprio(1);
#pragma unroll
    for (int nt = 0; nt < 4; nt++) {
      int dv = nt * 16 + l15;
      bf16x8 vb = *(const bf16x8*)&Vc[(dv * 4 + (quad ^ (dv & 3))) * 8];
      oacc[0][nt] = __builtin_amdgcn_mfma_f32_16x16x32_bf16(pa0, vb, oacc[0][nt], 0, 0, 0);
      oacc[1][nt] = __builtin_amdgcn_mfma_f32_16x16x32_bf16(pa1, vb, oacc[1][nt], 0, 0, 0);
    }
    __builtin_amdgcn_s_setprio(0);
  }
  __syncthreads();  // all waves done with K/V/P buffers before overlay

  // reduce lsum over quads (lane's lsum is for q=l15)
  lsum0 += __shfl_xor(lsum0, 16, 64); lsum0 += __shfl_xor(lsum0, 32, 64);
  lsum1 += __shfl_xor(lsum1, 16, 64); lsum1 += __shfl_xor(lsum1, 32, 64);

  float* OshF = (float*)smem;          // [8][2][16][68]
  float* lshF = OshF + 8 * 2 * 16 * 68;  // [8][2][16]
  if (lane < 16) {
    lshF[w * 32 + lane] = lsum0;
    lshF[w * 32 + 16 + lane] = lsum1;
  }
#pragma unroll
  for (int qi = 0; qi < 2; qi++)
#pragma unroll
    for (int nt = 0; nt < 4; nt++)
#pragma unroll
      for (int r = 0; r < 4; r++)
        OshF[(w * 2 + qi) * 1088 + (quad * 4 + r) * 68 + nt * 16 + l15] = oacc[qi][nt][r];
  __syncthreads();

  // combine the two KV halves, normalize, write concat (bf16)
  const int q = tid >> 2;            // 0..127
  const int dv0 = (tid & 3) * 16;    // 16 dv per thread
  const int qg2 = q >> 5, qi = (q >> 4) & 1, qr = q & 15;
  const float* pa = &OshF[(qg2 * 2 + qi) * 1088 + qr * 68 + dv0];
  const float* pb = &OshF[((qg2 + 4) * 2 + qi) * 1088 + qr * 68 + dv0];
  float4 a0 = *(const float4*)pa, a1 = *(const float4*)(pa + 4);
  float4 a2 = *(const float4*)(pa + 8), a3 = *(const float4*)(pa + 12);
  float4 b0 = *(const float4*)pb, b1 = *(const float4*)(pb + 4);
  float4 b2 = *(const float4*)(pb + 8), b3 = *(const float4*)(pb + 12);
  float li = 1.0f / (lshF[qg2 * 32 + qi * 16 + qr] + lshF[(qg2 + 4) * 32 + qi * 16 + qr]);
  union { u16 hh[8]; uint4 u4; } o0, o1;
  o0.hh[0] = f2bf((a0.x + b0.x) * li); o0.hh[1] = f2bf((a0.y + b0.y) * li);
  o0.hh[2] = f2bf((a0.z + b0.z) * li); o0.hh[3] = f2bf((a0.w + b0.w) * li);
  o0.hh[4] = f2bf((a1.x + b1.x) * li); o0.hh[5] = f2bf((a1.y + b1.y) * li);
  o0.hh[6] = f2bf((a1.z + b1.z) * li); o0.hh[7] = f2bf((a1.w + b1.w) * li);
  o1.hh[0] = f2bf((a2.x + b2.x) * li); o1.hh[1] = f2bf((a2.y + b2.y) * li);
  o1.hh[2] = f2bf((a2.z + b2.z) * li); o1.hh[3] = f2bf((a2.w + b2.w) * li);
  o1.hh[4] = f2bf((a3.x + b3.x) * li); o1.hh[5] = f2bf((a3.y + b3.y) * li);
  o1.hh[6] = f2bf((a3.z + b3.z) * li); o1.hh[7] = f2bf((a3.w + b3.w) * li);
  u16* orow = conc + (size_t)(qblk + q) * D_MODEL + h * 64 + dv0;
  *(uint4*)orow = o0.u4;
  *(uint4*)(orow + 8) = o1.u4;
}

// ---------- output GEMM: 128x64 tile clone of proj structure ----------
// Grid 256 = 1 block/CU exactly (was 512x64^2 @ 2/CU). 16 MFMA per 6 ds_read per
// wave-iter (was 8 per 4); half the blocks and barriers per unit work.
// XCD-swizzled: l = (bid%8)*32 + bid/8 (bijective: 256 = 8*32); l = m*16 + n.
// Per-XCD chunk: 2 m-panels x all n -> A 1MB + B 2MB < 4MB L2.
__global__ __launch_bounds__(256, 2) void out_gemm_k(
    const u16* __restrict__ A, const u16* __restrict__ Bt,
    const float* __restrict__ bias, float* __restrict__ out) {
  const int bid = blockIdx.x;
  const int l = (bid & 7) * 32 + (bid >> 3);   // bijective: 256 = 8*32
  const int m0 = (l >> 4) * 128, n0 = (l & 15) * 64;

  // u16: A x3 bufs @0 (16KB each), B x3 bufs @24576 (8KB each) -> 72KB
  __shared__ __align__(16) u16 smem[36864];
  const int tid = threadIdx.x;
  const int w = tid >> 6, lane = tid & 63, quad = lane >> 4, l15 = lane & 15;
  const int wm = (w >> 1) * 64, wn = (w & 1) * 32;
  const int pbA = w * 256, pbB = w * 128;

  f32x4 acc[4][2] = {};

  {  // prologue: k-step 0 -> buf0, k-step 1 -> buf1 (program order = vmcnt order)
#pragma unroll
    for (int b = 0; b < 2; b++) {
      const int k0 = b * 64;
      u16* As = smem + b * 8192;
      u16* Bs = smem + 24576 + b * 4096;
#pragma unroll
      for (int e = 0; e < 4; e++) {
        int p = pbA + e * 64 + lane;
        int r = p >> 3, cg = (p & 7) ^ (r & 7);
        gl16(&A[(size_t)(m0 + r) * D_MODEL + k0 + cg * 8], As + (pbA + e * 64) * 8);
      }
#pragma unroll
      for (int e = 0; e < 2; e++) {
        int p = pbB + e * 64 + lane;
        int r = p >> 3, cg = (p & 7) ^ (r & 7);
        gl16(&Bt[(size_t)(n0 + r) * D_MODEL + k0 + cg * 8], Bs + (pbB + e * 64) * 8);
      }
    }
  }
#pragma unroll
  for (int it = 0; it < 16; it++) {
    const int rd = it % 3;  // compile-time constant after full unroll
    if (it < 15) asm volatile("s_waitcnt vmcnt(6)" ::: "memory");
    else         asm volatile("s_waitcnt vmcnt(0)" ::: "memory");
    __builtin_amdgcn_s_barrier();
    __builtin_amdgcn_sched_barrier(0);  // pin: nothing (esp. ds_read/gl16) above barrier
    if (it < 14) {
      const int wr = (rd + 2) % 3;
      const int k0 = (it + 2) * 64;
      u16* As = smem + wr * 8192;
      u16* Bs = smem + 24576 + wr * 4096;
#pragma unroll
      for (int e = 0; e < 4; e++) {
        int p = pbA + e * 64 + lane;
        int r = p >> 3, cg = (p & 7) ^ (r & 7);
        gl16(&A[(size_t)(m0 + r) * D_MODEL + k0 + cg * 8], As + (pbA + e * 64) * 8);
      }
#pragma unroll
      for (int e = 0; e < 2; e++) {
        int p = pbB + e * 64 + lane;
        int r = p >> 3, cg = (p & 7) ^ (r & 7);
        gl16(&Bt[(size_t)(n0 + r) * D_MODEL + k0 + cg * 8], Bs + (pbB + e * 64) * 8);
      }
    }
    const u16* As = smem + rd * 8192;
    const u16* Bs = smem + 24576 + rd * 4096;
#pragma unroll
    for (int kc = 0; kc < 2; kc++) {
      bf16x8 af[4], bfr[2];
      const int c = kc * 4 + quad;
#pragma unroll
      for (int t = 0; t < 4; t++) {
        int ma = wm + t * 16 + l15;
        af[t] = *(const bf16x8*)&As[(ma * 8 + (c ^ (ma & 7))) * 8];
      }
#pragma unroll
      for (int t = 0; t < 2; t++) {
        int na = wn + t * 16 + l15;
        bfr[t] = *(const bf16x8*)&Bs[(na * 8 + (c ^ (na & 7))) * 8];
      }
      __builtin_amdgcn_s_setprio(1);
#pragma unroll
      for (int tm = 0; tm < 4; tm++)
#pragma unroll
        for (int tn = 0; tn < 2; tn++)
          acc[tm][tn] = __builtin_amdgcn_mfma_f32_16x16x32_bf16(af[tm], bfr[tn], acc[tm][tn], 0, 0, 0);
      __builtin_amdgcn_s_setprio(0);
    }
  }
#pragma unroll
  for (int tm = 0; tm < 4; tm++)
#pragma unroll
    for (int tn = 0; tn < 2; tn++)
#pragma unroll
      for (int r = 0; r < 4; r++) {
        int row = m0 + wm + tm * 16 + quad * 4 + r;
        int col = n0 + wn + tn * 16 + l15;
        out[(size_t)row * D_MODEL + col] = acc[tm][tn][r] + bias[col];
      }
}

extern "C" void kernel_launch(void* const* d_in, const int* in_sizes, int n_in,
                              void* d_out, int out_size, void* d_ws, size_t ws_size,
                              hipStream_t stream) {
  const float* Q  = (const float*)d_in[0];
  const float* K  = (const float*)d_in[1];
  const float* V  = (const float*)d_in[2];
  const float* Wq = (const float*)d_in[3];
  const float* bq = (const float*)d_in[4];
  const float* Wk = (const float*)d_in[5];
  const float* bk = (const float*)d_in[6];
  const float* Wv = (const float*)d_in[7];
  const float* bv = (const float*)d_in[8];
  const float* Wo = (const float*)d_in[9];
  const float* bo = (const float*)d_in[10];
  float* out = (float*)d_out;

  u16* ws = (u16*)d_ws;
  u16* QKVb = ws;                                   // 3*S*D
  u16* Wqt  = QKVb + (size_t)3 * S_LEN * D_MODEL;   // D*D each
  u16* Wkt  = Wqt + (size_t)D_MODEL * D_MODEL;
  u16* Wvt  = Wkt + (size_t)D_MODEL * D_MODEL;
  u16* Wot  = Wvt + (size_t)D_MODEL * D_MODEL;
  u16* qbuf = Wot + (size_t)D_MODEL * D_MODEL;      // S*D
  u16* kbuf = qbuf + (size_t)S_LEN * D_MODEL;       // S*D
  u16* vTb  = kbuf + (size_t)S_LEN * D_MODEL;       // D*S
  u16* conc = vTb + (size_t)S_LEN * D_MODEL;        // S*D

  prep_k<<<dim3(10240), 256, 0, stream>>>(Q, K, V, Wq, Wk, Wv, Wo,
                                          QKVb, Wqt, Wkt, Wvt, Wot);
  proj_gemm_k<<<dim3(768), 256, 0, stream>>>(
      QKVb, Wqt, Wkt, Wvt, bq, bk, bv, qbuf, kbuf, vTb);
  attn_k<<<dim3(256), 512, 0, stream>>>(qbuf, kbuf, vTb, conc);
  out_gemm_k<<<dim3(256), 256, 0, stream>>>(conc, Wot, bo, out);
}

// Round 12
// 154.561 us; speedup vs baseline: 1.0103x; 1.0103x over previous
//
#include <hip/hip_runtime.h>
#include <stdint.h>

#define S_LEN 2048
#define D_MODEL 1024
#define NH 16
#define DKV 64

typedef unsigned short u16;
typedef __bf16 bf16x8 __attribute__((ext_vector_type(8)));
typedef float f32x4 __attribute__((ext_vector_type(4)));

__device__ __forceinline__ u16 f2bf(float f) {
  union { float f; uint32_t u; } v; v.f = f;
  uint32_t r = v.u + 0x7FFFu + ((v.u >> 16) & 1u);
  return (u16)(r >> 16);
}
// pack two positive floats to bf16x2 (cheap round; softmax-normalized later)
// NOTE round-3/4 post-mortem: hand-asm v_cvt_pk/v_exp caused deterministic
// trans-hazard corruption. Compiler-known ops only.
__device__ __forceinline__ uint32_t pkbf(float lo, float hi) {
  union { float f; uint32_t u; } a, b; a.f = lo; b.f = hi;
  return ((b.u + 0x8000u) & 0xFFFF0000u) | ((a.u + 0x8000u) >> 16);
}
// async global->LDS 16B: lds dest is WAVE-UNIFORM base; HW adds lane*16
__device__ __forceinline__ void gl16(const u16* g, u16* l) {
  __builtin_amdgcn_global_load_lds(
      (const __attribute__((address_space(1))) unsigned int*)g,
      (__attribute__((address_space(3))) unsigned int*)l, 16, 0, 0);
}

// ---------- prep: W transposes ONLY (QKV conversion fused into proj) ----------
// 1D grid 4096: [0,3072) Wq/Wk/Wv transpose, [3072,4096) Wo transpose
__global__ __launch_bounds__(256) void prep_k(
    const float* __restrict__ Wq, const float* __restrict__ Wk,
    const float* __restrict__ Wv, const float* __restrict__ Wo,
    u16* __restrict__ Wqt, u16* __restrict__ Wkt, u16* __restrict__ Wvt,
    u16* __restrict__ Wot) {
  __shared__ float tile[32][33];
  const int idx = blockIdx.x;
  const float* ip; u16* op; int R, C, r0, c0;
  if (idx < 3072) {
    int which = idx >> 10, head = (idx & 1023) >> 6, tl = idx & 63;
    ip = ((which == 0) ? Wq : (which == 1) ? Wk : Wv) + (size_t)head * D_MODEL * DKV;
    op = ((which == 0) ? Wqt : (which == 1) ? Wkt : Wvt) + (size_t)head * D_MODEL * DKV;
    R = D_MODEL; C = DKV; c0 = (tl & 1) * 32; r0 = (tl >> 1) * 32;
  } else {
    int t = idx - 3072;
    ip = Wo; op = Wot; R = D_MODEL; C = D_MODEL;
    c0 = (t & 31) * 32; r0 = (t >> 5) * 32;
  }
  int tr = threadIdx.x >> 5, tc = threadIdx.x & 31;
#pragma unroll
  for (int i = 0; i < 4; i++)
    tile[tr + i * 8][tc] = ip[(size_t)(r0 + tr + i * 8) * C + c0 + tc];
  __syncthreads();
#pragma unroll
  for (int i = 0; i < 4; i++) {
    int c = tr + i * 8;
    op[(size_t)(c0 + c) * R + r0 + tc] = f2bf(tile[tc][c]);
  }
}

// ---------- projection GEMM with FUSED f32->bf16 A-staging ----------
// A = Q/K/V f32 read directly (per-XCD slice L2/L3-resident); convert in-register
// ((__bf16) cast -> compiler emits v_cvt_pk_bf16_f32, hazard-safe) and ds_write
// into the SAME swizzled layout gl16 produced: LDS[p*8] <- chunk (p&7)^(r&7).
// Simple 1-barrier dbuf (r6: proj is structure-insensitive). B stays gl16.
// Grid 768 = 3 blocks/CU. XCD-swizzled: l = (bid%8)*96 + bid/8.
__global__ __launch_bounds__(256, 2) void proj_gemm_k(
    const float* __restrict__ Qf, const float* __restrict__ Kf,
    const float* __restrict__ Vf, const u16* __restrict__ Wqt,
    const u16* __restrict__ Wkt, const u16* __restrict__ Wvt,
    const float* __restrict__ bq, const float* __restrict__ bk,
    const float* __restrict__ bv,
    u16* __restrict__ qb, u16* __restrict__ kb, u16* __restrict__ vT) {
  const int bid = blockIdx.x;
  const int l = (bid & 7) * 96 + (bid >> 3);   // bijective: 768 = 8*96
  const int z = l >> 8, rem = l & 255;
  const int m0 = (rem >> 4) * 128, n0 = (rem & 15) * 64;
  const float* A = (z == 0) ? Qf : (z == 1) ? Kf : Vf;
  const u16* Bt = (z == 0) ? Wqt : (z == 1) ? Wkt : Wvt;
  const float* bias = (z == 0) ? bq : (z == 1) ? bk : bv;
  const float scale = (z == 0) ? 0.18033688f : 1.0f;  // (1/8)*log2(e) folded into q

  // u16: A0@0 A1@8192 (16KB each), B0@16384 B1@20480 (8KB each) -> 48KB, 2 blk/CU
  __shared__ __align__(16) u16 smem[24576];
  const int tid = threadIdx.x;
  const int w = tid >> 6, lane = tid & 63, quad = lane >> 4, l15 = lane & 15;
  const int wm = (w >> 1) * 64, wn = (w & 1) * 32;
  const int pbA = w * 256, pbB = w * 128;

  f32x4 acc[4][2] = {};
  float4 fa[4][2];

  {  // prologue: stage k=0 into buf0 (A: load+cvt+write; B: gl16)
#pragma unroll
    for (int e = 0; e < 4; e++) {
      int p = pbA + e * 64 + lane, r = p >> 3, cg = (p & 7) ^ (r & 7);
      const float* src = &A[(size_t)(m0 + r) * D_MODEL + cg * 8];
      fa[e][0] = *(const float4*)src;
      fa[e][1] = *(const float4*)(src + 4);
    }
#pragma unroll
    for (int e = 0; e < 4; e++) {
      int p = pbA + e * 64 + lane;
      union { __bf16 b[8]; uint4 u4; } cv;
      cv.b[0] = (__bf16)fa[e][0].x; cv.b[1] = (__bf16)fa[e][0].y;
      cv.b[2] = (__bf16)fa[e][0].z; cv.b[3] = (__bf16)fa[e][0].w;
      cv.b[4] = (__bf16)fa[e][1].x; cv.b[5] = (__bf16)fa[e][1].y;
      cv.b[6] = (__bf16)fa[e][1].z; cv.b[7] = (__bf16)fa[e][1].w;
      *(uint4*)&smem[p * 8] = cv.u4;
    }
#pragma unroll
    for (int e = 0; e < 2; e++) {
      int p = pbB + e * 64 + lane, r = p >> 3, cg = (p & 7) ^ (r & 7);
      gl16(&Bt[(size_t)(n0 + r) * D_MODEL + cg * 8], smem + 16384 + (pbB + e * 64) * 8);
    }
  }

  for (int it = 0; it < 16; it++) {
    const int cur = it & 1;
    if (it < 15) {  // issue next A f32 loads; latency hides under barrier+compute
      const int k0 = (it + 1) * 64;
#pragma unroll
      for (int e = 0; e < 4; e++) {
        int p = pbA + e * 64 + lane, r = p >> 3, cg = (p & 7) ^ (r & 7);
        const float* src = &A[(size_t)(m0 + r) * D_MODEL + k0 + cg * 8];
        fa[e][0] = *(const float4*)src;
        fa[e][1] = *(const float4*)(src + 4);
      }
    }
    __syncthreads();  // buf[cur] (all waves' ds_writes + B gl16) visible
    const u16* As = smem + cur * 8192;
    const u16* Bs = smem + 16384 + cur * 4096;
#pragma unroll
    for (int kc = 0; kc < 2; kc++) {
      bf16x8 af[4], bfr[2];
      const int c = kc * 4 + quad;
#pragma unroll
      for (int t = 0; t < 4; t++) {
        int ma = wm + t * 16 + l15;
        af[t] = *(const bf16x8*)&As[(ma * 8 + (c ^ (ma & 7))) * 8];
      }
#pragma unroll
      for (int t = 0; t < 2; t++) {
        int na = wn + t * 16 + l15;
        bfr[t] = *(const bf16x8*)&Bs[(na * 8 + (c ^ (na & 7))) * 8];
      }
      __builtin_amdgcn_s_setprio(1);
#pragma unroll
      for (int tm = 0; tm < 4; tm++)
#pragma unroll
        for (int tn = 0; tn < 2; tn++)
          acc[tm][tn] = __builtin_amdgcn_mfma_f32_16x16x32_bf16(af[tm], bfr[tn], acc[tm][tn], 0, 0, 0);
      __builtin_amdgcn_s_setprio(0);
    }
    if (it < 15) {  // cvt + write next A into buf[cur^1]; B gl16 next
      u16* Aw = smem + (cur ^ 1) * 8192;
      u16* Bw = smem + 16384 + (cur ^ 1) * 4096;
#pragma unroll
      for (int e = 0; e < 4; e++) {
        int p = pbA + e * 64 + lane;
        union { __bf16 b[8]; uint4 u4; } cv;
        cv.b[0] = (__bf16)fa[e][0].x; cv.b[1] = (__bf16)fa[e][0].y;
        cv.b[2] = (__bf16)fa[e][0].z; cv.b[3] = (__bf16)fa[e][0].w;
        cv.b[4] = (__bf16)fa[e][1].x; cv.b[5] = (__bf16)fa[e][1].y;
        cv.b[6] = (__bf16)fa[e][1].z; cv.b[7] = (__bf16)fa[e][1].w;
        *(uint4*)&Aw[p * 8] = cv.u4;
      }
      const int k0 = (it + 1) * 64;
#pragma unroll
      for (int e = 0; e < 2; e++) {
        int p = pbB + e * 64 + lane, r = p >> 3, cg = (p & 7) ^ (r & 7);
        gl16(&Bt[(size_t)(n0 + r) * D_MODEL + k0 + cg * 8], Bw + (pbB + e * 64) * 8);
      }
    }
  }

  if (z < 2) {
    u16* O = (z == 0) ? qb : kb;
#pragma unroll
    for (int tm = 0; tm < 4; tm++)
#pragma unroll
      for (int tn = 0; tn < 2; tn++)
#pragma unroll
        for (int r = 0; r < 4; r++) {
          int row = m0 + wm + tm * 16 + quad * 4 + r;
          int col = n0 + wn + tn * 16 + l15;
          O[(size_t)row * D_MODEL + col] = f2bf((acc[tm][tn][r] + bias[col]) * scale);
        }
  } else {
#pragma unroll
    for (int tm = 0; tm < 4; tm++)
#pragma unroll
      for (int tn = 0; tn < 2; tn++) {
        int col = n0 + wn + tn * 16 + l15;
        int row0 = m0 + wm + tm * 16 + quad * 4;
        float b = bias[col];
        union { u16 h[4]; uint2 u2; } o;
#pragma unroll
        for (int r = 0; r < 4; r++) o.h[r] = f2bf(acc[tm][tn][r] + b);
        *(uint2*)&vT[(size_t)col * S_LEN + row0] = o.u2;
      }
  }
}

// ---------- attention: 32q-per-wave REUSE + 4-buf 3-deep counted-vmcnt ----------
// (round-10 state; r9/r10 differencing puts this at ~33.6 us)
__global__ __launch_bounds__(512) void attn_k(
    const u16* __restrict__ qb, const u16* __restrict__ kb,
    const u16* __restrict__ vT, u16* __restrict__ conc) {
  const int bid = blockIdx.x;
  const int l = (bid & 7) * 32 + (bid >> 3);   // bijective: 256 = 8*32
  const int h = l >> 4, qblk = (l & 15) * 128;
  const int tid = threadIdx.x;
  const int w = tid >> 6, lane = tid & 63, quad = lane >> 4, l15 = lane & 15;
  const int half = w >> 2, qg = w & 3;
  const int q0 = qblk + qg * 32;

  // u16 layout: K[2 half][4 buf][2048] @0 (32KB), V[2][4][2048] @16384 (32KB),
  //             P[8 waves][32*56] @32768 (28KB) -> 92KB, 1 block/CU.
  // epilogue overlays @0 as float OshF[8][2][16][68] + lshF[8][2][16] (70.7KB)
  __shared__ __align__(16) u16 smem[47104];
  u16* Kh = smem + half * 8192;
  u16* Vh = smem + 16384 + half * 8192;
  u16* Pw = smem + 32768 + w * 1792;

  // Q B-frags for TWO 16-row groups (qi): n=q=l15, k=dk=kc*32+quad*8+j
  bf16x8 qf[2][2];
#pragma unroll
  for (int qi = 0; qi < 2; qi++)
#pragma unroll
    for (int kc = 0; kc < 2; kc++)
      qf[qi][kc] = *(const bf16x8*)&qb[(size_t)(q0 + qi * 16 + l15) * D_MODEL + h * 64 + kc * 32 + quad * 8];

  const u16* kbase = kb + (size_t)h * 64;
  const u16* vbase = vT + (size_t)(h * 64) * S_LEN;

  // per-wave staging: 4 waves per half cover the 256 16B-chunks of each K/V tile
  const int p = qg * 64 + lane;                   // 0..255
  const int kr = p >> 3, kcg = (p & 7) ^ (kr & 7);
  const int vr = p >> 2, vcg = (p & 3) ^ (vr & 3);
  const size_t kgoff = (size_t)kr * D_MODEL + kcg * 8;
  const size_t vgoff = (size_t)vr * S_LEN + vcg * 8;
  const int ldsoff = qg * 512;                    // wave-uniform dest (HW adds lane*16)

  f32x4 oacc[2][4] = {};
  float lsum0 = 0.f, lsum1 = 0.f;

  {  // prologue: stage slots 0,1,2 (program order = vmcnt order)
#pragma unroll
    for (int s = 0; s < 3; s++) {
      const int t0 = half * 1024 + s * 32;
      gl16(kbase + (size_t)t0 * D_MODEL + kgoff, Kh + s * 2048 + ldsoff);
      gl16(vbase + t0 + vgoff, Vh + s * 2048 + ldsoff);
    }
  }

#pragma unroll
  for (int it = 0; it < 32; it++) {
    const int rd = it & 3;  // compile-time constant after full unroll
    if (it < 30)       asm volatile("s_waitcnt vmcnt(4)" ::: "memory");
    else if (it == 30) asm volatile("s_waitcnt vmcnt(2)" ::: "memory");
    else               asm volatile("s_waitcnt vmcnt(0)" ::: "memory");
    __builtin_amdgcn_s_barrier();   // all waves' buf[rd] chunks visible
    __builtin_amdgcn_sched_barrier(0);  // pin: nothing (esp. ds_read/gl16) above barrier
    if (it < 29) {                  // prefetch it+3 into buf[(it+3)&3]
      const int wr = (it + 3) & 3;
      const int t0n = half * 1024 + (it + 3) * 32;
      gl16(kbase + (size_t)t0n * D_MODEL + kgoff, Kh + wr * 2048 + ldsoff);
      gl16(vbase + t0n + vgoff, Vh + wr * 2048 + ldsoff);
    }
    const u16* Kc = Kh + rd * 2048;
    const u16* Vc = Vh + rd * 2048;

    // Sᵀ = K·Qᵀ : each K frag read feeds BOTH qi groups (2x reuse)
    f32x4 sacc[2][2] = {};
    __builtin_amdgcn_s_setprio(1);
#pragma unroll
    for (int kc = 0; kc < 2; kc++)
#pragma unroll
      for (int tn = 0; tn < 2; tn++) {
        int rr = tn * 16 + l15;
        bf16x8 ka = *(const bf16x8*)&Kc[(rr * 8 + ((kc * 4 + quad) ^ (rr & 7))) * 8];
        sacc[0][tn] = __builtin_amdgcn_mfma_f32_16x16x32_bf16(ka, qf[0][kc], sacc[0][tn], 0, 0, 0);
        sacc[1][tn] = __builtin_amdgcn_mfma_f32_16x16x32_bf16(ka, qf[1][kc], sacc[1][tn], 0, 0, 0);
      }
    __builtin_amdgcn_s_setprio(0);

    // p = 2^s (log2e folded into q); lane holds Sᵀ[t=tn*16+quad*4+r][q=l15] per qi
#pragma unroll
    for (int qi = 0; qi < 2; qi++)
#pragma unroll
      for (int tn = 0; tn < 2; tn++) {
        float p0 = __builtin_amdgcn_exp2f(sacc[qi][tn][0]);
        float p1 = __builtin_amdgcn_exp2f(sacc[qi][tn][1]);
        float p2 = __builtin_amdgcn_exp2f(sacc[qi][tn][2]);
        float p3 = __builtin_amdgcn_exp2f(sacc[qi][tn][3]);
        if (qi == 0) lsum0 += (p0 + p1) + (p2 + p3);
        else         lsum1 += (p0 + p1) + (p2 + p3);
        uint2 pw2; pw2.x = pkbf(p0, p1); pw2.y = pkbf(p2, p3);
        *(uint2*)&Pw[(qi * 16 + l15) * 56 + tn * 16 + quad * 4] = pw2;
      }

    // O += P·V : each V frag read feeds BOTH qi groups (2x reuse)
    bf16x8 pa0 = *(const bf16x8*)&Pw[(l15) * 56 + quad * 8];
    bf16x8 pa1 = *(const bf16x8*)&Pw[(16 + l15) * 56 + quad * 8];
    __builtin_amdgcn_s_setprio(1);
#pragma unroll
    for (int nt = 0; nt < 4; nt++) {
      int dv = nt * 16 + l15;
      bf16x8 vb = *(const bf16x8*)&Vc[(dv * 4 + (quad ^ (dv & 3))) * 8];
      oacc[0][nt] = __builtin_amdgcn_mfma_f32_16x16x32_bf16(pa0, vb, oacc[0][nt], 0, 0, 0);
      oacc[1][nt] = __builtin_amdgcn_mfma_f32_16x16x32_bf16(pa1, vb, oacc[1][nt], 0, 0, 0);
    }
    __builtin_amdgcn_s_setprio(0);
  }
  __syncthreads();  // all waves done with K/V/P buffers before overlay

  // reduce lsum over quads (lane's lsum is for q=l15)
  lsum0 += __shfl_xor(lsum0, 16, 64); lsum0 += __shfl_xor(lsum0, 32, 64);
  lsum1 += __shfl_xor(lsum1, 16, 64); lsum1 += __shfl_xor(lsum1, 32, 64);

  float* OshF = (float*)smem;          // [8][2][16][68]
  float* lshF = OshF + 8 * 2 * 16 * 68;  // [8][2][16]
  if (lane < 16) {
    lshF[w * 32 + lane] = lsum0;
    lshF[w * 32 + 16 + lane] = lsum1;
  }
#pragma unroll
  for (int qi = 0; qi < 2; qi++)
#pragma unroll
    for (int nt = 0; nt < 4; nt++)
#pragma unroll
      for (int r = 0; r < 4; r++)
        OshF[(w * 2 + qi) * 1088 + (quad * 4 + r) * 68 + nt * 16 + l15] = oacc[qi][nt][r];
  __syncthreads();

  // combine the two KV halves, normalize, write concat (bf16)
  const int q = tid >> 2;            // 0..127
  const int dv0 = (tid & 3) * 16;    // 16 dv per thread
  const int qg2 = q >> 5, qi = (q >> 4) & 1, qr = q & 15;
  const float* pa = &OshF[(qg2 * 2 + qi) * 1088 + qr * 68 + dv0];
  const float* pb = &OshF[((qg2 + 4) * 2 + qi) * 1088 + qr * 68 + dv0];
  float4 a0 = *(const float4*)pa, a1 = *(const float4*)(pa + 4);
  float4 a2 = *(const float4*)(pa + 8), a3 = *(const float4*)(pa + 12);
  float4 b0 = *(const float4*)pb, b1 = *(const float4*)(pb + 4);
  float4 b2 = *(const float4*)(pb + 8), b3 = *(const float4*)(pb + 12);
  float li = 1.0f / (lshF[qg2 * 32 + qi * 16 + qr] + lshF[(qg2 + 4) * 32 + qi * 16 + qr]);
  union { u16 hh[8]; uint4 u4; } o0, o1;
  o0.hh[0] = f2bf((a0.x + b0.x) * li); o0.hh[1] = f2bf((a0.y + b0.y) * li);
  o0.hh[2] = f2bf((a0.z + b0.z) * li); o0.hh[3] = f2bf((a0.w + b0.w) * li);
  o0.hh[4] = f2bf((a1.x + b1.x) * li); o0.hh[5] = f2bf((a1.y + b1.y) * li);
  o0.hh[6] = f2bf((a1.z + b1.z) * li); o0.hh[7] = f2bf((a1.w + b1.w) * li);
  o1.hh[0] = f2bf((a2.x + b2.x) * li); o1.hh[1] = f2bf((a2.y + b2.y) * li);
  o1.hh[2] = f2bf((a2.z + b2.z) * li); o1.hh[3] = f2bf((a2.w + b2.w) * li);
  o1.hh[4] = f2bf((a3.x + b3.x) * li); o1.hh[5] = f2bf((a3.y + b3.y) * li);
  o1.hh[6] = f2bf((a3.z + b3.z) * li); o1.hh[7] = f2bf((a3.w + b3.w) * li);
  u16* orow = conc + (size_t)(qblk + q) * D_MODEL + h * 64 + dv0;
  *(uint4*)orow = o0.u4;
  *(uint4*)(orow + 8) = o1.u4;
}

// ---------- output GEMM: 64x64 tile, BK=64, 4-buf 3-DEEP counted-vmcnt ----------
// (round-7 version: best measured for this stage)
__global__ __launch_bounds__(256, 2) void out_gemm_k(
    const u16* __restrict__ A, const u16* __restrict__ Bt,
    const float* __restrict__ bias, float* __restrict__ out) {
  const int bid = blockIdx.x;
  const int l = (bid & 7) * 64 + (bid >> 3);   // bijective: 512 = 8*64
  const int m0 = (l >> 4) * 64, n0 = (l & 15) * 64;
  __shared__ __align__(16) u16 smem[8 * 4096];  // A x4 @0, B x4 @16384 (8KB each)
  const int tid = threadIdx.x;
  const int w = tid >> 6, lane = tid & 63, quad = lane >> 4, l15 = lane & 15;
  const int wm = (w >> 1) * 32, wn = (w & 1) * 32;
  const int pb = w * 128;

  f32x4 acc[2][2] = {};
  {  // prologue: stage k-slots 0,1,2 (program order = vmcnt order)
#pragma unroll
    for (int s = 0; s < 3; s++) {
      const int k0 = s * 64;
#pragma unroll
      for (int e = 0; e < 2; e++) {
        int p = pb + e * 64 + lane;
        int r = p >> 3, cg = (p & 7) ^ (r & 7);
        gl16(&A[(size_t)(m0 + r) * D_MODEL + k0 + cg * 8], smem + s * 4096 + (pb + e * 64) * 8);
        gl16(&Bt[(size_t)(n0 + r) * D_MODEL + k0 + cg * 8], smem + 16384 + s * 4096 + (pb + e * 64) * 8);
      }
    }
  }
#pragma unroll
  for (int it = 0; it < 16; it++) {
    const int rd = it & 3;  // compile-time constant after full unroll
    if (it < 14)       asm volatile("s_waitcnt vmcnt(8)" ::: "memory");
    else if (it == 14) asm volatile("s_waitcnt vmcnt(4)" ::: "memory");
    else               asm volatile("s_waitcnt vmcnt(0)" ::: "memory");
    __builtin_amdgcn_s_barrier();
    __builtin_amdgcn_sched_barrier(0);  // pin: nothing above barrier
    if (it < 13) {
      const int wr = (it + 3) & 3;
      const int k0 = (it + 3) * 64;
      u16* As = smem + wr * 4096;
      u16* Bs = smem + 16384 + wr * 4096;
#pragma unroll
      for (int e = 0; e < 2; e++) {
        int p = pb + e * 64 + lane;
        int r = p >> 3, cg = (p & 7) ^ (r & 7);
        gl16(&A[(size_t)(m0 + r) * D_MODEL + k0 + cg * 8], As + (pb + e * 64) * 8);
        gl16(&Bt[(size_t)(n0 + r) * D_MODEL + k0 + cg * 8], Bs + (pb + e * 64) * 8);
      }
    }
    const u16* As = smem + rd * 4096;
    const u16* Bs = smem + 16384 + rd * 4096;
#pragma unroll
    for (int kc = 0; kc < 2; kc++) {
      const int c = kc * 4 + quad;
      bf16x8 af[2], bfr[2];
#pragma unroll
      for (int t = 0; t < 2; t++) {
        int ma = wm + t * 16 + l15, na = wn + t * 16 + l15;
        af[t] = *(const bf16x8*)&As[(ma * 8 + (c ^ (ma & 7))) * 8];
        bfr[t] = *(const bf16x8*)&Bs[(na * 8 + (c ^ (na & 7))) * 8];
      }
      __builtin_amdgcn_s_setprio(1);
#pragma unroll
      for (int tm = 0; tm < 2; tm++)
#pragma unroll
        for (int tn = 0; tn < 2; tn++)
          acc[tm][tn] = __builtin_amdgcn_mfma_f32_16x16x32_bf16(af[tm], bfr[tn], acc[tm][tn], 0, 0, 0);
      __builtin_amdgcn_s_setprio(0);
    }
  }
#pragma unroll
  for (int tm = 0; tm < 2; tm++)
#pragma unroll
    for (int tn = 0; tn < 2; tn++)
#pragma unroll
      for (int r = 0; r < 4; r++) {
        int row = m0 + wm + tm * 16 + quad * 4 + r;
        int col = n0 + wn + tn * 16 + l15;
        out[(size_t)row * D_MODEL + col] = acc[tm][tn][r] + bias[col];
      }
}

extern "C" void kernel_launch(void* const* d_in, const int* in_sizes, int n_in,
                              void* d_out, int out_size, void* d_ws, size_t ws_size,
                              hipStream_t stream) {
  const float* Q  = (const float*)d_in[0];
  const float* K  = (const float*)d_in[1];
  const float* V  = (const float*)d_in[2];
  const float* Wq = (const float*)d_in[3];
  const float* bq = (const float*)d_in[4];
  const float* Wk = (const float*)d_in[5];
  const float* bk = (const float*)d_in[6];
  const float* Wv = (const float*)d_in[7];
  const float* bv = (const float*)d_in[8];
  const float* Wo = (const float*)d_in[9];
  const float* bo = (const float*)d_in[10];
  float* out = (float*)d_out;

  u16* ws = (u16*)d_ws;
  u16* Wqt  = ws;                                   // D*D each
  u16* Wkt  = Wqt + (size_t)D_MODEL * D_MODEL;
  u16* Wvt  = Wkt + (size_t)D_MODEL * D_MODEL;
  u16* Wot  = Wvt + (size_t)D_MODEL * D_MODEL;
  u16* qbuf = Wot + (size_t)D_MODEL * D_MODEL;      // S*D
  u16* kbuf = qbuf + (size_t)S_LEN * D_MODEL;       // S*D
  u16* vTb  = kbuf + (size_t)S_LEN * D_MODEL;       // D*S
  u16* conc = vTb + (size_t)S_LEN * D_MODEL;        // S*D

  prep_k<<<dim3(4096), 256, 0, stream>>>(Wq, Wk, Wv, Wo, Wqt, Wkt, Wvt, Wot);
  proj_gemm_k<<<dim3(768), 256, 0, stream>>>(
      Q, K, V, Wqt, Wkt, Wvt, bq, bk, bv, qbuf, kbuf, vTb);
  attn_k<<<dim3(256), 512, 0, stream>>>(qbuf, kbuf, vTb, conc);
  out_gemm_k<<<dim3(512), 256, 0, stream>>>(conc, Wot, bo, out);
}